// Round 1
// baseline (883.307 us; speedup 1.0000x reference)
//
#include <hip/hip_runtime.h>

typedef __bf16 bf8 __attribute__((ext_vector_type(8)));
typedef float f4 __attribute__((ext_vector_type(4)));
typedef unsigned short us4 __attribute__((ext_vector_type(4)));
typedef unsigned int u32x4 __attribute__((ext_vector_type(4)));

#define MFMA16(a,b,c) __builtin_amdgcn_mfma_f32_16x16x32_bf16((a),(b),(c),0,0,0)

#define BLOCK 512
#define NWAVE 8

__device__ __forceinline__ unsigned short f2bfu(float f){
  __bf16 h = (__bf16)f;
  union { __bf16 b; unsigned short u; } v; v.b = h; return v.u;
}
__device__ __forceinline__ float ubfu(unsigned int u16){
  union { unsigned int i; float f; } v; v.i = u16 << 16; return v.f;
}

// Wave-local LDS fence (validated rounds 4-8, absmax 0.0).
__device__ __forceinline__ void wfence(){
  asm volatile("s_waitcnt lgkmcnt(0)" ::: "memory");
}

// LDS layout for weight staging (ushort element offsets)
#define OFF_W1   0
#define OFF_W2   2048
#define OFF_W3   6144
#define OFF_CW1  7168    // compact: k<16 half only
#define OFF_CW2  8192
#define OFF_CW3  12288
#define OFF_CW4  16384
#define OFF_ACT  17408
#define ACT_STRIDE 72
#define SMEM_US  (17408 + NWAVE*16*ACT_STRIDE)   // fused-kernel LDS (53248 B)
#define MSMEM_US 17408                            // mlp_phase LDS: act overlaps staging

#define BO_B1  0
#define BO_B2  64
#define BO_B3  128
#define BO_CB1 144
#define BO_CB2 208
#define BO_CB3 272
#define BO_CB4 336

template<int FIN,int FOUT,int KS,int MT>
__device__ __forceinline__ void stage_w(const float* w, unsigned short* dst){
  const int total = KS*MT*512;
  for (int e = threadIdx.x; e < total; e += BLOCK){
    int chunk = e >> 9;
    int s = chunk / MT, t = chunk % MT;
    int le = e & 511;
    int lane = le >> 3, j = le & 7;
    int q = lane >> 4, m = lane & 15;
    int i = s*32 + q*8 + j;
    int o = t*16 + m;
    dst[e] = (i < FIN && o < FOUT) ? f2bfu(w[i*FOUT + o]) : (unsigned short)0;
  }
}

__device__ __forceinline__ void stage_cw1(const float* w, unsigned short* dst){
  for (int e = threadIdx.x; e < 1024; e += BLOCK){
    int t = e >> 8;
    int le = e & 255;
    int lane = le >> 3, j = e & 7;
    int q = lane >> 4, m = lane & 15;
    dst[e] = f2bfu(w[(q*8+j)*64 + t*16 + m]);
  }
}

__device__ __forceinline__ void layer64(const unsigned short* wlds, const unsigned short* bias,
                                        unsigned short* act, int lane, bool relu){
  const int q = lane >> 4, m = lane & 15;
  bf8 b0 = *(const bf8*)(act + m*ACT_STRIDE + q*8);
  bf8 b1 = *(const bf8*)(act + m*ACT_STRIDE + 32 + q*8);
  f4 acc[4];
#pragma unroll
  for (int t = 0; t < 4; ++t){
    f4 c = {0.f,0.f,0.f,0.f};
    c = MFMA16(*(const bf8*)(wlds + ((0*4+t)*64+lane)*8), b0, c);
    c = MFMA16(*(const bf8*)(wlds + ((1*4+t)*64+lane)*8), b1, c);
    acc[t] = c;
  }
#pragma unroll
  for (int t = 0; t < 4; ++t){
    us4 bb = *(const us4*)(bias + t*16 + q*4);
    us4 pk;
#pragma unroll
    for (int r = 0; r < 4; ++r){
      float v = acc[t][r] + ubfu(bb[r]);
      if (relu) v = fmaxf(v, 0.f);
      pk[r] = f2bfu(v);
    }
    *(us4*)(act + m*ACT_STRIDE + t*16 + q*4) = pk;
  }
}

// Shared device code for the bias/weight staging preamble (fused kernel only).
#define STAGE_ALL_WEIGHTS()                                                  \
  stage_w<32,64,1,4>(w1,  smem+OFF_W1);                                      \
  stage_w<64,64,2,4>(w2,  smem+OFF_W2);                                      \
  stage_w<64,16,2,1>(w3,  smem+OFF_W3);                                      \
  stage_cw1(cw1, smem+OFF_CW1);                                              \
  stage_w<64,64,2,4>(cw2, smem+OFF_CW2);                                     \
  stage_w<64,64,2,4>(cw3, smem+OFF_CW3);                                     \
  stage_w<64, 3,2,1>(cw4, smem+OFF_CW4);                                     \
  {                                                                          \
    int t = threadIdx.x;                                                     \
    if (t < 64){                                                             \
      sbias[BO_B1 +t] = f2bfu(b1[t]);                                        \
      sbias[BO_B2 +t] = f2bfu(b2[t]);                                        \
      sbias[BO_CB1+t] = f2bfu(cb1[t]);                                       \
      sbias[BO_CB2+t] = f2bfu(cb2[t]);                                       \
      sbias[BO_CB3+t] = f2bfu(cb3[t]);                                       \
    }                                                                        \
    if (t < 16) sbias[BO_B3+t] = f2bfu(b3[t]);                               \
    if (t < 3)  sbias[BO_CB4+t] = f2bfu(cb4[t]);                             \
  }

// Old MLP body (fused fallback kernel only).
#define MLP_BODY(bfrag, gp)                                                  \
    {                                                                        \
      f4 acc[4];                                                             \
      _Pragma("unroll")                                                      \
      for (int t = 0; t < 4; ++t){                                           \
        f4 c = {0.f,0.f,0.f,0.f};                                            \
        acc[t] = MFMA16(*(const bf8*)(smem + OFF_W1 + (t*64+lane)*8), bfrag, c);\
      }                                                                      \
      _Pragma("unroll")                                                      \
      for (int t = 0; t < 4; ++t){                                           \
        us4 bb = *(const us4*)(sbias + BO_B1 + t*16 + q*4);                  \
        us4 pk;                                                              \
        _Pragma("unroll")                                                    \
        for (int r = 0; r < 4; ++r){                                         \
          float v = fmaxf(acc[t][r] + ubfu(bb[r]), 0.f);                     \
          pk[r] = f2bfu(v);                                                  \
        }                                                                    \
        *(us4*)(act + m*ACT_STRIDE + t*16 + q*4) = pk;                       \
      }                                                                      \
    }                                                                        \
    wfence();                                                                \
    layer64(smem+OFF_W2, sbias+BO_B2, act, lane, true);                      \
    wfence();                                                                \
    {                                                                        \
      bf8 b0 = *(const bf8*)(act + m*ACT_STRIDE + q*8);                      \
      bf8 b1 = *(const bf8*)(act + m*ACT_STRIDE + 32 + q*8);                 \
      f4 c = {0.f,0.f,0.f,0.f};                                              \
      c = MFMA16(*(const bf8*)(smem + OFF_W3 + lane*8), b0, c);              \
      c = MFMA16(*(const bf8*)(smem + OFF_W3 + (64+lane)*8), b1, c);         \
      us4 bb = *(const us4*)(sbias + BO_B3 + q*4);                           \
      us4 pk;                                                                \
      float d0 = 0.f;                                                        \
      _Pragma("unroll")                                                      \
      for (int r = 0; r < 4; ++r){                                           \
        float v = c[r] + ubfu(bb[r]);                                        \
        if (r == 0) d0 = v;                                                  \
        pk[r] = f2bfu(v);                                                    \
      }                                                                      \
      if (q == 0 && gp < nB) out[gp] = expf(d0);                             \
      *(us4*)(act + m*ACT_STRIDE + q*4) = pk;                                \
    }                                                                        \
    wfence();                                                                \
    {                                                                        \
      bf8 bc, aw[4];                                                         \
      if (q < 2){                                                            \
        bc = *(const bf8*)(act + m*ACT_STRIDE + q*8);                        \
        _Pragma("unroll")                                                    \
        for (int t = 0; t < 4; ++t)                                          \
          aw[t] = *(const bf8*)(smem + OFF_CW1 + (t*32+lane)*8);             \
      } else {                                                               \
        _Pragma("unroll")                                                    \
        for (int j = 0; j < 8; ++j) bc[j] = (__bf16)0.f;                     \
        _Pragma("unroll")                                                    \
        for (int t = 0; t < 4; ++t) aw[t] = bc;                              \
      }                                                                      \
      f4 acc[4];                                                             \
      _Pragma("unroll")                                                      \
      for (int t = 0; t < 4; ++t){                                           \
        f4 c = {0.f,0.f,0.f,0.f};                                            \
        acc[t] = MFMA16(aw[t], bc, c);                                       \
      }                                                                      \
      _Pragma("unroll")                                                      \
      for (int t = 0; t < 4; ++t){                                           \
        us4 bb = *(const us4*)(sbias + BO_CB1 + t*16 + q*4);                 \
        us4 pk;                                                              \
        _Pragma("unroll")                                                    \
        for (int r = 0; r < 4; ++r){                                         \
          float v = fmaxf(acc[t][r] + ubfu(bb[r]), 0.f);                     \
          pk[r] = f2bfu(v);                                                  \
        }                                                                    \
        *(us4*)(act + m*ACT_STRIDE + t*16 + q*4) = pk;                       \
      }                                                                      \
    }                                                                        \
    wfence();                                                                \
    layer64(smem+OFF_CW2, sbias+BO_CB2, act, lane, true);                    \
    wfence();                                                                \
    layer64(smem+OFF_CW3, sbias+BO_CB3, act, lane, true);                    \
    wfence();                                                                \
    {                                                                        \
      bf8 b0 = *(const bf8*)(act + m*ACT_STRIDE + q*8);                      \
      bf8 b1 = *(const bf8*)(act + m*ACT_STRIDE + 32 + q*8);                 \
      f4 c = {0.f,0.f,0.f,0.f};                                              \
      c = MFMA16(*(const bf8*)(smem + OFF_CW4 + lane*8), b0, c);             \
      c = MFMA16(*(const bf8*)(smem + OFF_CW4 + (64+lane)*8), b1, c);        \
      if (q == 0 && gp < nB){                                                \
        _Pragma("unroll")                                                    \
        for (int r = 0; r < 3; ++r){                                         \
          float v = c[r] + ubfu(sbias[BO_CB4 + r]);                          \
          out[nB + gp*3 + r] = 1.f/(1.f + expf(-v));                         \
        }                                                                    \
      }                                                                      \
    }                                                                        \
    wfence();

// ---------------------------------------------------------------------------
// Phase A: per-level hash encode with the level's FULL table in LDS (bf16x2
// packed, 64 KB). Kills the 64B-line L2 amplification: gathers are 4B LDS ops.
// grid = (point chunks, 16 levels). feat layout: [level][point] packed uint.
// Unroll 2: kernel is latency-bound (8-gather dependent chain at 50% occ) —
// doubling in-flight gathers is free ILP.
// ---------------------------------------------------------------------------
#define CH 16384
__global__ __launch_bounds__(512) void hash_phase(
    const float* __restrict__ xin, const float* __restrict__ tab,
    unsigned int* __restrict__ feat, int nB)
{
  __shared__ unsigned int stab[16384];
  __shared__ int sres[16];
  const int lvl = blockIdx.y;
  {
    const float2* t2 = (const float2*)tab + (lvl<<14);
    for (int e = threadIdx.x; e < 16384; e += 512){
      float2 v = t2[e];
      stab[e] = ((unsigned)f2bfu(v.y) << 16) | (unsigned)f2bfu(v.x);
    }
    if (threadIdx.x < 16){
      const int R[16] = {16,20,25,32,40,50,64,80,101,128,161,203,256,322,406,512};
      sres[threadIdx.x] = R[threadIdx.x];
    }
  }
  __syncthreads();

  const int res = sres[lvl];
  const float sc = 0.5f*(float)(res-1);
  const bool dense = (lvl < 3);              // 16^3,20^3,25^3 <= 16384
  unsigned int* fout = feat + (size_t)lvl * (size_t)nB;

  int pend = (blockIdx.x + 1) * CH; if (pend > nB) pend = nB;
#pragma unroll 2
  for (int p = blockIdx.x*CH + threadIdx.x; p < pend; p += 512){
    const float px = xin[p*3+0], py = xin[p*3+1], pz = xin[p*3+2];
    const float xs=(px+1.f)*sc, ys=(py+1.f)*sc, zs=(pz+1.f)*sc;
    const float fx=floorf(xs), fy=floorf(ys), fz=floorf(zs);
    const float wx=xs-fx, wy=ys-fy, wz=zs-fz;
    int ix0=min(max((int)fx,0),res-1);
    int iy0=min(max((int)fy,0),res-1);
    int iz0=min(max((int)fz,0),res-1);
    int ix1=min(ix0+1,res-1), iy1=min(iy0+1,res-1), iz1=min(iz0+1,res-1);
    unsigned X0,X1,Y0,Y1,Z0,Z1;
    if (dense){
      X0=(unsigned)ix0;            X1=(unsigned)ix1;
      Y0=(unsigned)(res*iy0);      Y1=(unsigned)(res*iy1);
      Z0=(unsigned)(res*res*iz0);  Z1=(unsigned)(res*res*iz1);
    } else {
      X0=(unsigned)ix0;                 X1=(unsigned)ix1;
      Y0=(unsigned)iy0*2654435761u;     Y1=(unsigned)iy1*2654435761u;
      Z0=(unsigned)iz0*805459861u;      Z1=(unsigned)iz1*805459861u;
    }
    const float wx0=1.f-wx, wy0=1.f-wy, wz0=1.f-wz;
    float f0=0.f, f1=0.f;
#pragma unroll
    for (int c = 0; c < 8; ++c){
      unsigned xc = (c&1)?X1:X0;
      unsigned yc = (c&2)?Y1:Y0;
      unsigned zc = (c&4)?Z1:Z0;
      unsigned idx = dense ? (xc+yc+zc) : ((xc^yc^zc)&16383u);
      unsigned tv = stab[idx];
      float wc = ((c&1)?wx:wx0) * ((c&2)?wy:wy0) * ((c&4)?wz:wz0);
      f0 += wc*ubfu(tv << 16);
      f1 += wc*ubfu(tv & 0xffff0000u);
    }
    fout[p] = ((unsigned)f2bfu(f1) << 16) | (unsigned)f2bfu(f0);
  }
}

// ---------------------------------------------------------------------------
// Phase B: MLP over precomputed features.
// v2: all weight fragments hoisted to VGPRs once per wave (removes ~36
// ds_read_b128/iter + addressing VALU + bank conflicts); biases folded into
// MFMA C-init as f32 (removes lshl+add per output element, improves accuracy);
// activation scratch overlaps the consumed weight-staging LDS (34.8 KB ->
// 3-4 blocks/CU instead of 2).
// ---------------------------------------------------------------------------
__global__ __launch_bounds__(BLOCK, 6) void mlp_phase(
    const unsigned int* __restrict__ feat,
    const float* __restrict__ w1,  const float* __restrict__ b1,
    const float* __restrict__ w2,  const float* __restrict__ b2,
    const float* __restrict__ w3,  const float* __restrict__ b3,
    const float* __restrict__ cw1, const float* __restrict__ cb1,
    const float* __restrict__ cw2, const float* __restrict__ cb2,
    const float* __restrict__ cw3, const float* __restrict__ cb3,
    const float* __restrict__ cw4, const float* __restrict__ cb4,
    float* __restrict__ out, int nB)
{
  __shared__ __align__(16) unsigned short smem[MSMEM_US];
  stage_w<32,64,1,4>(w1,  smem+OFF_W1);
  stage_w<64,64,2,4>(w2,  smem+OFF_W2);
  stage_w<64,16,2,1>(w3,  smem+OFF_W3);
  stage_cw1(cw1, smem+OFF_CW1);
  stage_w<64,64,2,4>(cw2, smem+OFF_CW2);
  stage_w<64,64,2,4>(cw3, smem+OFF_CW3);
  stage_w<64, 3,2,1>(cw4, smem+OFF_CW4);
  __syncthreads();

  const int lane = threadIdx.x & 63, wv = threadIdx.x >> 6;
  const int q = lane >> 4, m = lane & 15;

  // ---- hoist all weight fragments into VGPRs (one-time, wave-invariant) ----
  bf8 w1f[4], w2f[2][4], w3f[2], cw1f[4], cw2f[2][4], cw3f[2][4], cw4f[2];
#pragma unroll
  for (int t = 0; t < 4; ++t)
    w1f[t] = *(const bf8*)(smem + OFF_W1 + (t*64+lane)*8);
#pragma unroll
  for (int s = 0; s < 2; ++s)
#pragma unroll
    for (int t = 0; t < 4; ++t){
      w2f[s][t]  = *(const bf8*)(smem + OFF_W2  + ((s*4+t)*64+lane)*8);
      cw2f[s][t] = *(const bf8*)(smem + OFF_CW2 + ((s*4+t)*64+lane)*8);
      cw3f[s][t] = *(const bf8*)(smem + OFF_CW3 + ((s*4+t)*64+lane)*8);
    }
  w3f[0]  = *(const bf8*)(smem + OFF_W3  + lane*8);
  w3f[1]  = *(const bf8*)(smem + OFF_W3  + (64+lane)*8);
  cw4f[0] = *(const bf8*)(smem + OFF_CW4 + lane*8);
  cw4f[1] = *(const bf8*)(smem + OFF_CW4 + (64+lane)*8);
  if (q < 2){
#pragma unroll
    for (int t = 0; t < 4; ++t)
      cw1f[t] = *(const bf8*)(smem + OFF_CW1 + (t*32+lane)*8);
  } else {
    bf8 z;
#pragma unroll
    for (int j = 0; j < 8; ++j) z[j] = (__bf16)0.f;
#pragma unroll
    for (int t = 0; t < 4; ++t) cw1f[t] = z;
  }

  // ---- biases as f32 C-init vectors: element r of tile t = bias[t*16+q*4+r]
  f4 b1v[4], b2v[4], cb1v[4], cb2v[4], cb3v[4];
#pragma unroll
  for (int t = 0; t < 4; ++t){
    b1v[t]  = *(const f4*)(b1  + t*16 + q*4);
    b2v[t]  = *(const f4*)(b2  + t*16 + q*4);
    cb1v[t] = *(const f4*)(cb1 + t*16 + q*4);
    cb2v[t] = *(const f4*)(cb2 + t*16 + q*4);
    cb3v[t] = *(const f4*)(cb3 + t*16 + q*4);
  }
  f4 b3v = *(const f4*)(b3 + q*4);
  f4 c4v = {0.f,0.f,0.f,0.f};
  if (q == 0){ c4v[0] = cb4[0]; c4v[1] = cb4[1]; c4v[2] = cb4[2]; }

  __syncthreads();   // all waves' fragments loaded; staging LDS becomes act scratch

  unsigned short* act = smem + wv*16*ACT_STRIDE;   // 8*1152 us <= 17408 us

  for (int it = 0; it < 4; ++it){
    const int gp  = blockIdx.x*BLOCK + wv*64 + it*16 + m;
    const int gpl = min(gp, nB-1);
    union { u32x4 u; bf8 b; } fb;
    fb.u[0] = feat[(size_t)(4*q    )*(size_t)nB + gpl];
    fb.u[1] = feat[(size_t)(4*q + 1)*(size_t)nB + gpl];
    fb.u[2] = feat[(size_t)(4*q + 2)*(size_t)nB + gpl];
    fb.u[3] = feat[(size_t)(4*q + 3)*(size_t)nB + gpl];

    // L1: 32 -> 64, relu
    {
      f4 a[4];
#pragma unroll
      for (int t = 0; t < 4; ++t) a[t] = MFMA16(w1f[t], fb.b, b1v[t]);
#pragma unroll
      for (int t = 0; t < 4; ++t){
        us4 pk;
#pragma unroll
        for (int r = 0; r < 4; ++r) pk[r] = f2bfu(fmaxf(a[t][r], 0.f));
        *(us4*)(act + m*ACT_STRIDE + t*16 + q*4) = pk;
      }
    }
    wfence();
    // L2: 64 -> 64, relu
    {
      bf8 x0 = *(const bf8*)(act + m*ACT_STRIDE + q*8);
      bf8 x1 = *(const bf8*)(act + m*ACT_STRIDE + 32 + q*8);
      f4 a[4];
#pragma unroll
      for (int t = 0; t < 4; ++t){
        f4 c = MFMA16(w2f[0][t], x0, b2v[t]);
        a[t]  = MFMA16(w2f[1][t], x1, c);
      }
#pragma unroll
      for (int t = 0; t < 4; ++t){
        us4 pk;
#pragma unroll
        for (int r = 0; r < 4; ++r) pk[r] = f2bfu(fmaxf(a[t][r], 0.f));
        *(us4*)(act + m*ACT_STRIDE + t*16 + q*4) = pk;
      }
    }
    wfence();
    // L3: 64 -> 16 (no relu); sigma = exp(d0)
    {
      bf8 x0 = *(const bf8*)(act + m*ACT_STRIDE + q*8);
      bf8 x1 = *(const bf8*)(act + m*ACT_STRIDE + 32 + q*8);
      f4 c = MFMA16(w3f[0], x0, b3v);
      c = MFMA16(w3f[1], x1, c);
      us4 pk;
#pragma unroll
      for (int r = 0; r < 4; ++r) pk[r] = f2bfu(c[r]);
      if (q == 0 && gp < nB) out[gp] = expf(c[0]);
      *(us4*)(act + m*ACT_STRIDE + q*4) = pk;
    }
    wfence();
    // C1: 16 -> 64, relu (rows >=16 are zero: q>=2 lanes contribute zeros)
    {
      bf8 bc;
      if (q < 2){
        bc = *(const bf8*)(act + m*ACT_STRIDE + q*8);
      } else {
#pragma unroll
        for (int j = 0; j < 8; ++j) bc[j] = (__bf16)0.f;
      }
      f4 a[4];
#pragma unroll
      for (int t = 0; t < 4; ++t) a[t] = MFMA16(cw1f[t], bc, cb1v[t]);
#pragma unroll
      for (int t = 0; t < 4; ++t){
        us4 pk;
#pragma unroll
        for (int r = 0; r < 4; ++r) pk[r] = f2bfu(fmaxf(a[t][r], 0.f));
        *(us4*)(act + m*ACT_STRIDE + t*16 + q*4) = pk;
      }
    }
    wfence();
    // C2: 64 -> 64, relu
    {
      bf8 x0 = *(const bf8*)(act + m*ACT_STRIDE + q*8);
      bf8 x1 = *(const bf8*)(act + m*ACT_STRIDE + 32 + q*8);
      f4 a[4];
#pragma unroll
      for (int t = 0; t < 4; ++t){
        f4 c = MFMA16(cw2f[0][t], x0, cb2v[t]);
        a[t]  = MFMA16(cw2f[1][t], x1, c);
      }
#pragma unroll
      for (int t = 0; t < 4; ++t){
        us4 pk;
#pragma unroll
        for (int r = 0; r < 4; ++r) pk[r] = f2bfu(fmaxf(a[t][r], 0.f));
        *(us4*)(act + m*ACT_STRIDE + t*16 + q*4) = pk;
      }
    }
    wfence();
    // C3: 64 -> 64, relu
    {
      bf8 x0 = *(const bf8*)(act + m*ACT_STRIDE + q*8);
      bf8 x1 = *(const bf8*)(act + m*ACT_STRIDE + 32 + q*8);
      f4 a[4];
#pragma unroll
      for (int t = 0; t < 4; ++t){
        f4 c = MFMA16(cw3f[0][t], x0, cb3v[t]);
        a[t]  = MFMA16(cw3f[1][t], x1, c);
      }
#pragma unroll
      for (int t = 0; t < 4; ++t){
        us4 pk;
#pragma unroll
        for (int r = 0; r < 4; ++r) pk[r] = f2bfu(fmaxf(a[t][r], 0.f));
        *(us4*)(act + m*ACT_STRIDE + t*16 + q*4) = pk;
      }
    }
    wfence();
    // C4: 64 -> 3, sigmoid
    {
      bf8 x0 = *(const bf8*)(act + m*ACT_STRIDE + q*8);
      bf8 x1 = *(const bf8*)(act + m*ACT_STRIDE + 32 + q*8);
      f4 c = MFMA16(cw4f[0], x0, c4v);
      c = MFMA16(cw4f[1], x1, c);
      if (q == 0 && gp < nB){
#pragma unroll
        for (int r = 0; r < 3; ++r)
          out[nB + gp*3 + r] = 1.f/(1.f + expf(-c[r]));
      }
    }
    wfence();
  }
}

// ---------------------------------------------------------------------------
// Fallback: round-8 fused kernel (used only if workspace < 64 MB).
// ---------------------------------------------------------------------------
__global__ __launch_bounds__(BLOCK) void nerf_fused(
    const float* __restrict__ xin, const float* __restrict__ tab,
    const float* __restrict__ w1,  const float* __restrict__ b1,
    const float* __restrict__ w2,  const float* __restrict__ b2,
    const float* __restrict__ w3,  const float* __restrict__ b3,
    const float* __restrict__ cw1, const float* __restrict__ cb1,
    const float* __restrict__ cw2, const float* __restrict__ cb2,
    const float* __restrict__ cw3, const float* __restrict__ cb3,
    const float* __restrict__ cw4, const float* __restrict__ cb4,
    float* __restrict__ out, int nB)
{
  __shared__ __align__(16) unsigned short smem[SMEM_US];
  __shared__ __align__(16) unsigned short sbias[344];
  __shared__ int sres[16];
  STAGE_ALL_WEIGHTS();
  if (threadIdx.x < 16){
    const int R[16] = {16,20,25,32,40,50,64,80,101,128,161,203,256,322,406,512};
    sres[threadIdx.x] = R[threadIdx.x];
  }
  __syncthreads();

  const int lane = threadIdx.x & 63, wv = threadIdx.x >> 6;
  const int q = lane >> 4, m = lane & 15;
  unsigned short* act = smem + OFF_ACT + wv*16*ACT_STRIDE;

  int res_[4];
#pragma unroll
  for (int d = 0; d < 4; ++d) res_[d] = sres[4*q + d];

  for (int it = 0; it < 4; ++it){
    const int gp  = blockIdx.x*BLOCK + wv*64 + it*16 + m;
    const int gpl = min(gp, nB-1);
    const float px = xin[gpl*3+0];
    const float py = xin[gpl*3+1];
    const float pz = xin[gpl*3+2];

    bf8 bfrag;
#pragma unroll
    for (int d = 0; d < 4; ++d){
      const int lvl = 4*q + d;
      const int res = res_[d];
      const float sc = 0.5f*(float)(res-1);
      const float xs=(px+1.f)*sc, ys=(py+1.f)*sc, zs=(pz+1.f)*sc;
      const float fx=floorf(xs), fy=floorf(ys), fz=floorf(zs);
      const float wx=xs-fx, wy=ys-fy, wz=zs-fz;
      int ix0=min(max((int)fx,0),res-1);
      int iy0=min(max((int)fy,0),res-1);
      int iz0=min(max((int)fz,0),res-1);
      int ix1=min(ix0+1,res-1), iy1=min(iy0+1,res-1), iz1=min(iz0+1,res-1);
      const bool dense = (lvl < 3);
      unsigned X0,X1,Y0,Y1,Z0,Z1;
      if (dense){
        X0=(unsigned)ix0;            X1=(unsigned)ix1;
        Y0=(unsigned)(res*iy0);      Y1=(unsigned)(res*iy1);
        Z0=(unsigned)(res*res*iz0);  Z1=(unsigned)(res*res*iz1);
      } else {
        X0=(unsigned)ix0;                 X1=(unsigned)ix1;
        Y0=(unsigned)iy0*2654435761u;     Y1=(unsigned)iy1*2654435761u;
        Z0=(unsigned)iz0*805459861u;      Z1=(unsigned)iz1*805459861u;
      }
      const float wx0=1.f-wx, wy0=1.f-wy, wz0=1.f-wz;
      float f0=0.f, f1=0.f;
      const float2* tl = (const float2*)tab + (lvl<<14);
#pragma unroll
      for (int c = 0; c < 8; ++c){
        unsigned xc = (c&1)?X1:X0;
        unsigned yc = (c&2)?Y1:Y0;
        unsigned zc = (c&4)?Z1:Z0;
        unsigned idx = dense ? (xc+yc+zc) : ((xc^yc^zc)&16383u);
        float2 tv = tl[idx];
        float wc = ((c&1)?wx:wx0) * ((c&2)?wy:wy0) * ((c&4)?wz:wz0);
        f0 += wc*tv.x;
        f1 += wc*tv.y;
      }
      bfrag[2*d]   = (__bf16)f0;
      bfrag[2*d+1] = (__bf16)f1;
    }
    MLP_BODY(bfrag, gp)
  }
}

extern "C" void kernel_launch(void* const* d_in, const int* in_sizes, int n_in,
                              void* d_out, int out_size, void* d_ws, size_t ws_size,
                              hipStream_t stream) {
  (void)n_in; (void)out_size;
  const int nB = in_sizes[0] / 3;
  const float* xin = (const float*)d_in[0];
  const float* tab = (const float*)d_in[1];
  const float *w1=(const float*)d_in[2],  *b1=(const float*)d_in[3];
  const float *w2=(const float*)d_in[4],  *b2=(const float*)d_in[5];
  const float *w3=(const float*)d_in[6],  *b3=(const float*)d_in[7];
  const float *cw1=(const float*)d_in[8], *cb1=(const float*)d_in[9];
  const float *cw2=(const float*)d_in[10],*cb2=(const float*)d_in[11];
  const float *cw3=(const float*)d_in[12],*cb3=(const float*)d_in[13];
  const float *cw4=(const float*)d_in[14],*cb4=(const float*)d_in[15];
  float* out = (float*)d_out;

  const size_t need = (size_t)nB * 16u * 4u;   // feat[level][point] packed uint
  if (ws_size >= need){
    dim3 ga((nB + CH - 1) / CH, 16);
    hash_phase<<<ga, dim3(512), 0, stream>>>(xin, tab, (unsigned int*)d_ws, nB);
    const int blocks = (nB + BLOCK - 1) / BLOCK;
    mlp_phase<<<dim3(blocks), dim3(BLOCK), 0, stream>>>(
        (const unsigned int*)d_ws, w1,b1,w2,b2,w3,b3,
        cw1,cb1,cw2,cb2,cw3,cb3,cw4,cb4, out, nB);
  } else {
    const int blocks = (nB + BLOCK - 1) / BLOCK;
    nerf_fused<<<dim3(blocks), dim3(BLOCK), 0, stream>>>(
        xin, tab, w1,b1,w2,b2,w3,b3,
        cw1,cb1,cw2,cb2,cw3,cb3,cw4,cb4, out, nB);
  }
}

// Round 2
// 229.672 us; speedup vs baseline: 3.8460x; 3.8460x over previous
//
#include <hip/hip_runtime.h>

typedef __bf16 bf8 __attribute__((ext_vector_type(8)));
typedef float f4 __attribute__((ext_vector_type(4)));
typedef unsigned short us4 __attribute__((ext_vector_type(4)));
typedef unsigned int u32x4 __attribute__((ext_vector_type(4)));

#define MFMA16(a,b,c) __builtin_amdgcn_mfma_f32_16x16x32_bf16((a),(b),(c),0,0,0)

#define BLOCK 512
#define NWAVE 8

__device__ __forceinline__ unsigned short f2bfu(float f){
  __bf16 h = (__bf16)f;
  union { __bf16 b; unsigned short u; } v; v.b = h; return v.u;
}
__device__ __forceinline__ float ubfu(unsigned int u16){
  union { unsigned int i; float f; } v; v.i = u16 << 16; return v.f;
}

// Wave-local LDS fence (validated rounds 4-8, absmax 0.0).
__device__ __forceinline__ void wfence(){
  asm volatile("s_waitcnt lgkmcnt(0)" ::: "memory");
}

// LDS layout for weight staging (ushort element offsets)
#define OFF_W1   0
#define OFF_W2   2048
#define OFF_W3   6144
#define OFF_CW1  7168    // compact: k<16 half only
#define OFF_CW2  8192
#define OFF_CW3  12288
#define OFF_CW4  16384
#define OFF_ACT  17408
#define ACT_STRIDE 72
#define SMEM_US  (17408 + NWAVE*16*ACT_STRIDE)   // fused-kernel LDS (53248 B)
#define MSMEM_US 17408                            // mlp_phase LDS: act overlaps staging

#define BO_B1  0
#define BO_B2  64
#define BO_B3  128
#define BO_CB1 144
#define BO_CB2 208
#define BO_CB3 272
#define BO_CB4 336

// f32 bias offsets (floats) for mlp_phase
#define FB_B1  0
#define FB_B2  64
#define FB_CB1 128
#define FB_CB2 192
#define FB_CB3 256
#define FB_B3  320
#define FB_CB4 336

template<int FIN,int FOUT,int KS,int MT>
__device__ __forceinline__ void stage_w(const float* w, unsigned short* dst){
  const int total = KS*MT*512;
  for (int e = threadIdx.x; e < total; e += BLOCK){
    int chunk = e >> 9;
    int s = chunk / MT, t = chunk % MT;
    int le = e & 511;
    int lane = le >> 3, j = le & 7;
    int q = lane >> 4, m = lane & 15;
    int i = s*32 + q*8 + j;
    int o = t*16 + m;
    dst[e] = (i < FIN && o < FOUT) ? f2bfu(w[i*FOUT + o]) : (unsigned short)0;
  }
}

__device__ __forceinline__ void stage_cw1(const float* w, unsigned short* dst){
  for (int e = threadIdx.x; e < 1024; e += BLOCK){
    int t = e >> 8;
    int le = e & 255;
    int lane = le >> 3, j = e & 7;
    int q = lane >> 4, m = lane & 15;
    dst[e] = f2bfu(w[(q*8+j)*64 + t*16 + m]);
  }
}

__device__ __forceinline__ void layer64(const unsigned short* wlds, const unsigned short* bias,
                                        unsigned short* act, int lane, bool relu){
  const int q = lane >> 4, m = lane & 15;
  bf8 b0 = *(const bf8*)(act + m*ACT_STRIDE + q*8);
  bf8 b1 = *(const bf8*)(act + m*ACT_STRIDE + 32 + q*8);
  f4 acc[4];
#pragma unroll
  for (int t = 0; t < 4; ++t){
    f4 c = {0.f,0.f,0.f,0.f};
    c = MFMA16(*(const bf8*)(wlds + ((0*4+t)*64+lane)*8), b0, c);
    c = MFMA16(*(const bf8*)(wlds + ((1*4+t)*64+lane)*8), b1, c);
    acc[t] = c;
  }
#pragma unroll
  for (int t = 0; t < 4; ++t){
    us4 bb = *(const us4*)(bias + t*16 + q*4);
    us4 pk;
#pragma unroll
    for (int r = 0; r < 4; ++r){
      float v = acc[t][r] + ubfu(bb[r]);
      if (relu) v = fmaxf(v, 0.f);
      pk[r] = f2bfu(v);
    }
    *(us4*)(act + m*ACT_STRIDE + t*16 + q*4) = pk;
  }
}

// Shared device code for the bias/weight staging preamble (fused kernel only).
#define STAGE_ALL_WEIGHTS()                                                  \
  stage_w<32,64,1,4>(w1,  smem+OFF_W1);                                      \
  stage_w<64,64,2,4>(w2,  smem+OFF_W2);                                      \
  stage_w<64,16,2,1>(w3,  smem+OFF_W3);                                      \
  stage_cw1(cw1, smem+OFF_CW1);                                              \
  stage_w<64,64,2,4>(cw2, smem+OFF_CW2);                                     \
  stage_w<64,64,2,4>(cw3, smem+OFF_CW3);                                     \
  stage_w<64, 3,2,1>(cw4, smem+OFF_CW4);                                     \
  {                                                                          \
    int t = threadIdx.x;                                                     \
    if (t < 64){                                                             \
      sbias[BO_B1 +t] = f2bfu(b1[t]);                                        \
      sbias[BO_B2 +t] = f2bfu(b2[t]);                                        \
      sbias[BO_CB1+t] = f2bfu(cb1[t]);                                       \
      sbias[BO_CB2+t] = f2bfu(cb2[t]);                                       \
      sbias[BO_CB3+t] = f2bfu(cb3[t]);                                       \
    }                                                                        \
    if (t < 16) sbias[BO_B3+t] = f2bfu(b3[t]);                               \
    if (t < 3)  sbias[BO_CB4+t] = f2bfu(cb4[t]);                             \
  }

// Old MLP body (fused fallback kernel only).
#define MLP_BODY(bfrag, gp)                                                  \
    {                                                                        \
      f4 acc[4];                                                             \
      _Pragma("unroll")                                                      \
      for (int t = 0; t < 4; ++t){                                           \
        f4 c = {0.f,0.f,0.f,0.f};                                            \
        acc[t] = MFMA16(*(const bf8*)(smem + OFF_W1 + (t*64+lane)*8), bfrag, c);\
      }                                                                      \
      _Pragma("unroll")                                                      \
      for (int t = 0; t < 4; ++t){                                           \
        us4 bb = *(const us4*)(sbias + BO_B1 + t*16 + q*4);                  \
        us4 pk;                                                              \
        _Pragma("unroll")                                                    \
        for (int r = 0; r < 4; ++r){                                         \
          float v = fmaxf(acc[t][r] + ubfu(bb[r]), 0.f);                     \
          pk[r] = f2bfu(v);                                                  \
        }                                                                    \
        *(us4*)(act + m*ACT_STRIDE + t*16 + q*4) = pk;                       \
      }                                                                      \
    }                                                                        \
    wfence();                                                                \
    layer64(smem+OFF_W2, sbias+BO_B2, act, lane, true);                      \
    wfence();                                                                \
    {                                                                        \
      bf8 b0 = *(const bf8*)(act + m*ACT_STRIDE + q*8);                      \
      bf8 b1 = *(const bf8*)(act + m*ACT_STRIDE + 32 + q*8);                 \
      f4 c = {0.f,0.f,0.f,0.f};                                              \
      c = MFMA16(*(const bf8*)(smem + OFF_W3 + lane*8), b0, c);              \
      c = MFMA16(*(const bf8*)(smem + OFF_W3 + (64+lane)*8), b1, c);         \
      us4 bb = *(const us4*)(sbias + BO_B3 + q*4);                           \
      us4 pk;                                                                \
      float d0 = 0.f;                                                        \
      _Pragma("unroll")                                                      \
      for (int r = 0; r < 4; ++r){                                           \
        float v = c[r] + ubfu(bb[r]);                                        \
        if (r == 0) d0 = v;                                                  \
        pk[r] = f2bfu(v);                                                    \
      }                                                                      \
      if (q == 0 && gp < nB) out[gp] = expf(d0);                             \
      *(us4*)(act + m*ACT_STRIDE + q*4) = pk;                                \
    }                                                                        \
    wfence();                                                                \
    {                                                                        \
      bf8 bc, aw[4];                                                         \
      if (q < 2){                                                            \
        bc = *(const bf8*)(act + m*ACT_STRIDE + q*8);                        \
        _Pragma("unroll")                                                    \
        for (int t = 0; t < 4; ++t)                                          \
          aw[t] = *(const bf8*)(smem + OFF_CW1 + (t*32+lane)*8);             \
      } else {                                                               \
        _Pragma("unroll")                                                    \
        for (int j = 0; j < 8; ++j) bc[j] = (__bf16)0.f;                     \
        _Pragma("unroll")                                                    \
        for (int t = 0; t < 4; ++t) aw[t] = bc;                              \
      }                                                                      \
      f4 acc[4];                                                             \
      _Pragma("unroll")                                                      \
      for (int t = 0; t < 4; ++t){                                           \
        f4 c = {0.f,0.f,0.f,0.f};                                            \
        acc[t] = MFMA16(aw[t], bc, c);                                       \
      }                                                                      \
      _Pragma("unroll")                                                      \
      for (int t = 0; t < 4; ++t){                                           \
        us4 bb = *(const us4*)(sbias + BO_CB1 + t*16 + q*4);                 \
        us4 pk;                                                              \
        _Pragma("unroll")                                                    \
        for (int r = 0; r < 4; ++r){                                         \
          float v = fmaxf(acc[t][r] + ubfu(bb[r]), 0.f);                     \
          pk[r] = f2bfu(v);                                                  \
        }                                                                    \
        *(us4*)(act + m*ACT_STRIDE + t*16 + q*4) = pk;                       \
      }                                                                      \
    }                                                                        \
    wfence();                                                                \
    layer64(smem+OFF_CW2, sbias+BO_CB2, act, lane, true);                    \
    wfence();                                                                \
    layer64(smem+OFF_CW3, sbias+BO_CB3, act, lane, true);                    \
    wfence();                                                                \
    {                                                                        \
      bf8 b0 = *(const bf8*)(act + m*ACT_STRIDE + q*8);                      \
      bf8 b1 = *(const bf8*)(act + m*ACT_STRIDE + 32 + q*8);                 \
      f4 c = {0.f,0.f,0.f,0.f};                                              \
      c = MFMA16(*(const bf8*)(smem + OFF_CW4 + lane*8), b0, c);             \
      c = MFMA16(*(const bf8*)(smem + OFF_CW4 + (64+lane)*8), b1, c);        \
      if (q == 0 && gp < nB){                                                \
        _Pragma("unroll")                                                    \
        for (int r = 0; r < 3; ++r){                                         \
          float v = c[r] + ubfu(sbias[BO_CB4 + r]);                          \
          out[nB + gp*3 + r] = 1.f/(1.f + expf(-v));                         \
        }                                                                    \
      }                                                                      \
    }                                                                        \
    wfence();

// ---------------------------------------------------------------------------
// Phase A: per-level hash encode with the level's FULL table in LDS (bf16x2
// packed, 64 KB). Kills the 64B-line L2 amplification: gathers are 4B LDS ops.
// grid = (point chunks, 16 levels). feat layout: [level][point] packed uint.
// (round-0 version; the unroll-2 experiment was neutral-to-negative)
// ---------------------------------------------------------------------------
#define CH 16384
__global__ __launch_bounds__(512) void hash_phase(
    const float* __restrict__ xin, const float* __restrict__ tab,
    unsigned int* __restrict__ feat, int nB)
{
  __shared__ unsigned int stab[16384];
  __shared__ int sres[16];
  const int lvl = blockIdx.y;
  {
    const float2* t2 = (const float2*)tab + (lvl<<14);
    for (int e = threadIdx.x; e < 16384; e += 512){
      float2 v = t2[e];
      stab[e] = ((unsigned)f2bfu(v.y) << 16) | (unsigned)f2bfu(v.x);
    }
    if (threadIdx.x < 16){
      const int R[16] = {16,20,25,32,40,50,64,80,101,128,161,203,256,322,406,512};
      sres[threadIdx.x] = R[threadIdx.x];
    }
  }
  __syncthreads();

  const int res = sres[lvl];
  const float sc = 0.5f*(float)(res-1);
  const bool dense = (lvl < 3);              // 16^3,20^3,25^3 <= 16384
  unsigned int* fout = feat + (size_t)lvl * (size_t)nB;

  int pend = (blockIdx.x + 1) * CH; if (pend > nB) pend = nB;
  for (int p = blockIdx.x*CH + threadIdx.x; p < pend; p += 512){
    const float px = xin[p*3+0], py = xin[p*3+1], pz = xin[p*3+2];
    const float xs=(px+1.f)*sc, ys=(py+1.f)*sc, zs=(pz+1.f)*sc;
    const float fx=floorf(xs), fy=floorf(ys), fz=floorf(zs);
    const float wx=xs-fx, wy=ys-fy, wz=zs-fz;
    int ix0=min(max((int)fx,0),res-1);
    int iy0=min(max((int)fy,0),res-1);
    int iz0=min(max((int)fz,0),res-1);
    int ix1=min(ix0+1,res-1), iy1=min(iy0+1,res-1), iz1=min(iz0+1,res-1);
    unsigned X0,X1,Y0,Y1,Z0,Z1;
    if (dense){
      X0=(unsigned)ix0;            X1=(unsigned)ix1;
      Y0=(unsigned)(res*iy0);      Y1=(unsigned)(res*iy1);
      Z0=(unsigned)(res*res*iz0);  Z1=(unsigned)(res*res*iz1);
    } else {
      X0=(unsigned)ix0;                 X1=(unsigned)ix1;
      Y0=(unsigned)iy0*2654435761u;     Y1=(unsigned)iy1*2654435761u;
      Z0=(unsigned)iz0*805459861u;      Z1=(unsigned)iz1*805459861u;
    }
    const float wx0=1.f-wx, wy0=1.f-wy, wz0=1.f-wz;
    float f0=0.f, f1=0.f;
#pragma unroll
    for (int c = 0; c < 8; ++c){
      unsigned xc = (c&1)?X1:X0;
      unsigned yc = (c&2)?Y1:Y0;
      unsigned zc = (c&4)?Z1:Z0;
      unsigned idx = dense ? (xc+yc+zc) : ((xc^yc^zc)&16383u);
      unsigned tv = stab[idx];
      float wc = ((c&1)?wx:wx0) * ((c&2)?wy:wy0) * ((c&4)?wz:wz0);
      f0 += wc*ubfu(tv << 16);
      f1 += wc*ubfu(tv & 0xffff0000u);
    }
    fout[p] = ((unsigned)f2bfu(f1) << 16) | (unsigned)f2bfu(f0);
  }
}

// ---------------------------------------------------------------------------
// Phase B: MLP over precomputed features.
// v3: weight fragments hoisted to VGPRs (144 regs); 64-wide biases stay in
// LDS as f32 and feed the MFMA C-operand via broadcast ds_read_b128 (saves
// 80 VGPRs vs v2 -> total ~210 < 256, so __launch_bounds__(512,2) caps the
// allocator WITHOUT spilling — v2's (512,6) cap at ~85 VGPRs spilled every
// fragment to scratch: 2.5 GB/launch scratch traffic, 782 us).
// feat loads software-prefetched one iteration ahead (only 2 waves/SIMD of
// TLP remain at this register budget).
// ---------------------------------------------------------------------------
__global__ __launch_bounds__(BLOCK, 2) void mlp_phase(
    const unsigned int* __restrict__ feat,
    const float* __restrict__ w1,  const float* __restrict__ b1,
    const float* __restrict__ w2,  const float* __restrict__ b2,
    const float* __restrict__ w3,  const float* __restrict__ b3,
    const float* __restrict__ cw1, const float* __restrict__ cb1,
    const float* __restrict__ cw2, const float* __restrict__ cb2,
    const float* __restrict__ cw3, const float* __restrict__ cb3,
    const float* __restrict__ cw4, const float* __restrict__ cb4,
    float* __restrict__ out, int nB)
{
  __shared__ __align__(16) unsigned short smem[MSMEM_US];
  __shared__ __align__(16) float sbf[340];
  stage_w<32,64,1,4>(w1,  smem+OFF_W1);
  stage_w<64,64,2,4>(w2,  smem+OFF_W2);
  stage_w<64,16,2,1>(w3,  smem+OFF_W3);
  stage_cw1(cw1, smem+OFF_CW1);
  stage_w<64,64,2,4>(cw2, smem+OFF_CW2);
  stage_w<64,64,2,4>(cw3, smem+OFF_CW3);
  stage_w<64, 3,2,1>(cw4, smem+OFF_CW4);
  {
    int t = threadIdx.x;
    if (t < 64){
      sbf[FB_B1 +t] = b1[t];
      sbf[FB_B2 +t] = b2[t];
      sbf[FB_CB1+t] = cb1[t];
      sbf[FB_CB2+t] = cb2[t];
      sbf[FB_CB3+t] = cb3[t];
    }
    if (t < 16) sbf[FB_B3+t] = b3[t];
    if (t < 4)  sbf[FB_CB4+t] = (t < 3) ? cb4[t] : 0.f;
  }
  __syncthreads();

  const int lane = threadIdx.x & 63, wv = threadIdx.x >> 6;
  const int q = lane >> 4, m = lane & 15;

  // ---- hoist all weight fragments into VGPRs (one-time, wave-invariant) ----
  bf8 w1f[4], w2f[2][4], w3f[2], cw1f[4], cw2f[2][4], cw3f[2][4], cw4f[2];
#pragma unroll
  for (int t = 0; t < 4; ++t)
    w1f[t] = *(const bf8*)(smem + OFF_W1 + (t*64+lane)*8);
#pragma unroll
  for (int s = 0; s < 2; ++s)
#pragma unroll
    for (int t = 0; t < 4; ++t){
      w2f[s][t]  = *(const bf8*)(smem + OFF_W2  + ((s*4+t)*64+lane)*8);
      cw2f[s][t] = *(const bf8*)(smem + OFF_CW2 + ((s*4+t)*64+lane)*8);
      cw3f[s][t] = *(const bf8*)(smem + OFF_CW3 + ((s*4+t)*64+lane)*8);
    }
  w3f[0]  = *(const bf8*)(smem + OFF_W3  + lane*8);
  w3f[1]  = *(const bf8*)(smem + OFF_W3  + (64+lane)*8);
  cw4f[0] = *(const bf8*)(smem + OFF_CW4 + lane*8);
  cw4f[1] = *(const bf8*)(smem + OFF_CW4 + (64+lane)*8);
  if (q < 2){
#pragma unroll
    for (int t = 0; t < 4; ++t)
      cw1f[t] = *(const bf8*)(smem + OFF_CW1 + (t*32+lane)*8);
  } else {
    bf8 z;
#pragma unroll
    for (int j = 0; j < 8; ++j) z[j] = (__bf16)0.f;
#pragma unroll
    for (int t = 0; t < 4; ++t) cw1f[t] = z;
  }

  // small biases in VGPRs (8 regs); 64-wide biases stay in LDS (sbf)
  f4 b3v = *(const f4*)(sbf + FB_B3 + q*4);
  f4 c4v = {0.f,0.f,0.f,0.f};
  if (q == 0) c4v = *(const f4*)(sbf + FB_CB4);

  __syncthreads();   // all waves' fragments loaded; staging LDS becomes act scratch

  unsigned short* act = smem + wv*16*ACT_STRIDE;   // 8*1152 us <= 17408 us

  const int gbase = blockIdx.x*BLOCK + wv*64 + m;
  u32x4 fcur, fnxt;
  {
    const int g = min(gbase, nB-1);
    fcur[0] = feat[(size_t)(4*q    )*(size_t)nB + g];
    fcur[1] = feat[(size_t)(4*q + 1)*(size_t)nB + g];
    fcur[2] = feat[(size_t)(4*q + 2)*(size_t)nB + g];
    fcur[3] = feat[(size_t)(4*q + 3)*(size_t)nB + g];
  }

  for (int it = 0; it < 4; ++it){
    const int gp = gbase + it*16;
    if (it < 3){
      const int g = min(gp + 16, nB-1);
      fnxt[0] = feat[(size_t)(4*q    )*(size_t)nB + g];
      fnxt[1] = feat[(size_t)(4*q + 1)*(size_t)nB + g];
      fnxt[2] = feat[(size_t)(4*q + 2)*(size_t)nB + g];
      fnxt[3] = feat[(size_t)(4*q + 3)*(size_t)nB + g];
    }
    union { u32x4 u; bf8 b; } fb; fb.u = fcur;

    // L1: 32 -> 64, relu
    {
      f4 a[4];
#pragma unroll
      for (int t = 0; t < 4; ++t)
        a[t] = MFMA16(w1f[t], fb.b, *(const f4*)(sbf + FB_B1 + t*16 + q*4));
#pragma unroll
      for (int t = 0; t < 4; ++t){
        us4 pk;
#pragma unroll
        for (int r = 0; r < 4; ++r) pk[r] = f2bfu(fmaxf(a[t][r], 0.f));
        *(us4*)(act + m*ACT_STRIDE + t*16 + q*4) = pk;
      }
    }
    wfence();
    // L2: 64 -> 64, relu
    {
      bf8 x0 = *(const bf8*)(act + m*ACT_STRIDE + q*8);
      bf8 x1 = *(const bf8*)(act + m*ACT_STRIDE + 32 + q*8);
      f4 a[4];
#pragma unroll
      for (int t = 0; t < 4; ++t){
        f4 c = MFMA16(w2f[0][t], x0, *(const f4*)(sbf + FB_B2 + t*16 + q*4));
        a[t]  = MFMA16(w2f[1][t], x1, c);
      }
#pragma unroll
      for (int t = 0; t < 4; ++t){
        us4 pk;
#pragma unroll
        for (int r = 0; r < 4; ++r) pk[r] = f2bfu(fmaxf(a[t][r], 0.f));
        *(us4*)(act + m*ACT_STRIDE + t*16 + q*4) = pk;
      }
    }
    wfence();
    // L3: 64 -> 16 (no relu); sigma = exp(d0)
    {
      bf8 x0 = *(const bf8*)(act + m*ACT_STRIDE + q*8);
      bf8 x1 = *(const bf8*)(act + m*ACT_STRIDE + 32 + q*8);
      f4 c = MFMA16(w3f[0], x0, b3v);
      c = MFMA16(w3f[1], x1, c);
      us4 pk;
#pragma unroll
      for (int r = 0; r < 4; ++r) pk[r] = f2bfu(c[r]);
      if (q == 0 && gp < nB) out[gp] = expf(c[0]);
      *(us4*)(act + m*ACT_STRIDE + q*4) = pk;
    }
    wfence();
    // C1: 16 -> 64, relu (rows >=16 are zero: q>=2 lanes contribute zeros)
    {
      bf8 bc;
      if (q < 2){
        bc = *(const bf8*)(act + m*ACT_STRIDE + q*8);
      } else {
#pragma unroll
        for (int j = 0; j < 8; ++j) bc[j] = (__bf16)0.f;
      }
      f4 a[4];
#pragma unroll
      for (int t = 0; t < 4; ++t)
        a[t] = MFMA16(cw1f[t], bc, *(const f4*)(sbf + FB_CB1 + t*16 + q*4));
#pragma unroll
      for (int t = 0; t < 4; ++t){
        us4 pk;
#pragma unroll
        for (int r = 0; r < 4; ++r) pk[r] = f2bfu(fmaxf(a[t][r], 0.f));
        *(us4*)(act + m*ACT_STRIDE + t*16 + q*4) = pk;
      }
    }
    wfence();
    // C2: 64 -> 64, relu
    {
      bf8 x0 = *(const bf8*)(act + m*ACT_STRIDE + q*8);
      bf8 x1 = *(const bf8*)(act + m*ACT_STRIDE + 32 + q*8);
      f4 a[4];
#pragma unroll
      for (int t = 0; t < 4; ++t){
        f4 c = MFMA16(cw2f[0][t], x0, *(const f4*)(sbf + FB_CB2 + t*16 + q*4));
        a[t]  = MFMA16(cw2f[1][t], x1, c);
      }
#pragma unroll
      for (int t = 0; t < 4; ++t){
        us4 pk;
#pragma unroll
        for (int r = 0; r < 4; ++r) pk[r] = f2bfu(fmaxf(a[t][r], 0.f));
        *(us4*)(act + m*ACT_STRIDE + t*16 + q*4) = pk;
      }
    }
    wfence();
    // C3: 64 -> 64, relu
    {
      bf8 x0 = *(const bf8*)(act + m*ACT_STRIDE + q*8);
      bf8 x1 = *(const bf8*)(act + m*ACT_STRIDE + 32 + q*8);
      f4 a[4];
#pragma unroll
      for (int t = 0; t < 4; ++t){
        f4 c = MFMA16(cw3f[0][t], x0, *(const f4*)(sbf + FB_CB3 + t*16 + q*4));
        a[t]  = MFMA16(cw3f[1][t], x1, c);
      }
#pragma unroll
      for (int t = 0; t < 4; ++t){
        us4 pk;
#pragma unroll
        for (int r = 0; r < 4; ++r) pk[r] = f2bfu(fmaxf(a[t][r], 0.f));
        *(us4*)(act + m*ACT_STRIDE + t*16 + q*4) = pk;
      }
    }
    wfence();
    // C4: 64 -> 3, sigmoid
    {
      bf8 x0 = *(const bf8*)(act + m*ACT_STRIDE + q*8);
      bf8 x1 = *(const bf8*)(act + m*ACT_STRIDE + 32 + q*8);
      f4 c = MFMA16(cw4f[0], x0, c4v);
      c = MFMA16(cw4f[1], x1, c);
      if (q == 0 && gp < nB){
#pragma unroll
        for (int r = 0; r < 3; ++r)
          out[nB + gp*3 + r] = 1.f/(1.f + expf(-c[r]));
      }
    }
    wfence();
    fcur = fnxt;
  }
}

// ---------------------------------------------------------------------------
// Fallback: round-8 fused kernel (used only if workspace < 64 MB).
// ---------------------------------------------------------------------------
__global__ __launch_bounds__(BLOCK) void nerf_fused(
    const float* __restrict__ xin, const float* __restrict__ tab,
    const float* __restrict__ w1,  const float* __restrict__ b1,
    const float* __restrict__ w2,  const float* __restrict__ b2,
    const float* __restrict__ w3,  const float* __restrict__ b3,
    const float* __restrict__ cw1, const float* __restrict__ cb1,
    const float* __restrict__ cw2, const float* __restrict__ cb2,
    const float* __restrict__ cw3, const float* __restrict__ cb3,
    const float* __restrict__ cw4, const float* __restrict__ cb4,
    float* __restrict__ out, int nB)
{
  __shared__ __align__(16) unsigned short smem[SMEM_US];
  __shared__ __align__(16) unsigned short sbias[344];
  __shared__ int sres[16];
  STAGE_ALL_WEIGHTS();
  if (threadIdx.x < 16){
    const int R[16] = {16,20,25,32,40,50,64,80,101,128,161,203,256,322,406,512};
    sres[threadIdx.x] = R[threadIdx.x];
  }
  __syncthreads();

  const int lane = threadIdx.x & 63, wv = threadIdx.x >> 6;
  const int q = lane >> 4, m = lane & 15;
  unsigned short* act = smem + OFF_ACT + wv*16*ACT_STRIDE;

  int res_[4];
#pragma unroll
  for (int d = 0; d < 4; ++d) res_[d] = sres[4*q + d];

  for (int it = 0; it < 4; ++it){
    const int gp  = blockIdx.x*BLOCK + wv*64 + it*16 + m;
    const int gpl = min(gp, nB-1);
    const float px = xin[gpl*3+0];
    const float py = xin[gpl*3+1];
    const float pz = xin[gpl*3+2];

    bf8 bfrag;
#pragma unroll
    for (int d = 0; d < 4; ++d){
      const int lvl = 4*q + d;
      const int res = res_[d];
      const float sc = 0.5f*(float)(res-1);
      const float xs=(px+1.f)*sc, ys=(py+1.f)*sc, zs=(pz+1.f)*sc;
      const float fx=floorf(xs), fy=floorf(ys), fz=floorf(zs);
      const float wx=xs-fx, wy=ys-fy, wz=zs-fz;
      int ix0=min(max((int)fx,0),res-1);
      int iy0=min(max((int)fy,0),res-1);
      int iz0=min(max((int)fz,0),res-1);
      int ix1=min(ix0+1,res-1), iy1=min(iy0+1,res-1), iz1=min(iz0+1,res-1);
      const bool dense = (lvl < 3);
      unsigned X0,X1,Y0,Y1,Z0,Z1;
      if (dense){
        X0=(unsigned)ix0;            X1=(unsigned)ix1;
        Y0=(unsigned)(res*iy0);      Y1=(unsigned)(res*iy1);
        Z0=(unsigned)(res*res*iz0);  Z1=(unsigned)(res*res*iz1);
      } else {
        X0=(unsigned)ix0;                 X1=(unsigned)ix1;
        Y0=(unsigned)iy0*2654435761u;     Y1=(unsigned)iy1*2654435761u;
        Z0=(unsigned)iz0*805459861u;      Z1=(unsigned)iz1*805459861u;
      }
      const float wx0=1.f-wx, wy0=1.f-wy, wz0=1.f-wz;
      float f0=0.f, f1=0.f;
      const float2* tl = (const float2*)tab + (lvl<<14);
#pragma unroll
      for (int c = 0; c < 8; ++c){
        unsigned xc = (c&1)?X1:X0;
        unsigned yc = (c&2)?Y1:Y0;
        unsigned zc = (c&4)?Z1:Z0;
        unsigned idx = dense ? (xc+yc+zc) : ((xc^yc^zc)&16383u);
        float2 tv = tl[idx];
        float wc = ((c&1)?wx:wx0) * ((c&2)?wy:wy0) * ((c&4)?wz:wz0);
        f0 += wc*tv.x;
        f1 += wc*tv.y;
      }
      bfrag[2*d]   = (__bf16)f0;
      bfrag[2*d+1] = (__bf16)f1;
    }
    MLP_BODY(bfrag, gp)
  }
}

extern "C" void kernel_launch(void* const* d_in, const int* in_sizes, int n_in,
                              void* d_out, int out_size, void* d_ws, size_t ws_size,
                              hipStream_t stream) {
  (void)n_in; (void)out_size;
  const int nB = in_sizes[0] / 3;
  const float* xin = (const float*)d_in[0];
  const float* tab = (const float*)d_in[1];
  const float *w1=(const float*)d_in[2],  *b1=(const float*)d_in[3];
  const float *w2=(const float*)d_in[4],  *b2=(const float*)d_in[5];
  const float *w3=(const float*)d_in[6],  *b3=(const float*)d_in[7];
  const float *cw1=(const float*)d_in[8], *cb1=(const float*)d_in[9];
  const float *cw2=(const float*)d_in[10],*cb2=(const float*)d_in[11];
  const float *cw3=(const float*)d_in[12],*cb3=(const float*)d_in[13];
  const float *cw4=(const float*)d_in[14],*cb4=(const float*)d_in[15];
  float* out = (float*)d_out;

  const size_t need = (size_t)nB * 16u * 4u;   // feat[level][point] packed uint
  if (ws_size >= need){
    dim3 ga((nB + CH - 1) / CH, 16);
    hash_phase<<<ga, dim3(512), 0, stream>>>(xin, tab, (unsigned int*)d_ws, nB);
    const int blocks = (nB + BLOCK - 1) / BLOCK;
    mlp_phase<<<dim3(blocks), dim3(BLOCK), 0, stream>>>(
        (const unsigned int*)d_ws, w1,b1,w2,b2,w3,b3,
        cw1,cb1,cw2,cb2,cw3,cb3,cw4,cb4, out, nB);
  } else {
    const int blocks = (nB + BLOCK - 1) / BLOCK;
    nerf_fused<<<dim3(blocks), dim3(BLOCK), 0, stream>>>(
        xin, tab, w1,b1,w2,b2,w3,b3,
        cw1,cb1,cw2,cb2,cw3,cb3,cw4,cb4, out, nB);
  }
}